// Round 12
// baseline (79.251 us; speedup 1.0000x reference)
//
#include <hip/hip_runtime.h>
#include <hip/hip_bf16.h>

#define HH 8
#define SEQL 4096
#define DD 128
#define NBLK 64
#define LOCAL_B 16
#define MBIAS 12.0f
#define EP_STR 132
#define SPLIT_Q0 14
#define NSPLIT (NBLK - SPLIT_Q0)            // 50
#define UNITS_PER_H (SPLIT_Q0 + NSPLIT * 2) // 114

typedef __attribute__((ext_vector_type(8))) short bf16x8;
typedef __attribute__((ext_vector_type(4))) float f32x4;
typedef unsigned short ushort_t;

typedef const __attribute__((address_space(1))) unsigned int gu32;
typedef __attribute__((address_space(3))) unsigned int lu32;

__device__ __forceinline__ unsigned short f2bf(float x) {
    union { float f; unsigned u; } a; a.f = x;
    unsigned r = a.u + 0x7FFFu + ((a.u >> 16) & 1u);
    return (unsigned short)(r >> 16);
}

__device__ __forceinline__ unsigned cvtpk_bf16(float lo, float hi) {
    unsigned r;
    asm("v_cvt_pk_bf16_f32 %0, %1, %2" : "=v"(r) : "v"(lo), "v"(hi));
    return r;
}

__device__ __forceinline__ void gload16(const void* src, void* ldsdst) {
    __builtin_amdgcn_global_load_lds((gu32*)src, (lu32*)ldsdst, 16, 0, 0);
}

// ---------------- fused prepass: K f32->bf16 flat; V f32 [H][S][D] -> bf16 Vt [H][D][S] ----------------
#define T_STR 136
__global__ void prep(const float* __restrict__ k, const float* __restrict__ v,
                     ushort_t* __restrict__ kb, ushort_t* __restrict__ vt) {
    __shared__ ushort_t t[64 * T_STR];
    int bid = blockIdx.x;
    int tid = threadIdx.x;
    if (bid < 2048) {
        int idx = (bid * 256 + tid) * 8;
        const float4* s = (const float4*)(k + idx);
        float4 a = s[0], b = s[1];
        union { bf16x8 v8; ushort_t u[8]; } p;
        p.u[0] = f2bf(a.x); p.u[1] = f2bf(a.y); p.u[2] = f2bf(a.z); p.u[3] = f2bf(a.w);
        p.u[4] = f2bf(b.x); p.u[5] = f2bf(b.y); p.u[6] = f2bf(b.z); p.u[7] = f2bf(b.w);
        *(bf16x8*)(kb + idx) = p.v8;
        return;
    }
    int g = bid - 2048;
    int h  = g >> 6;
    int sb = g & 63;
    const float* vp = v + ((size_t)h * SEQL + sb * 64) * DD;
    {
        int col = (tid & 15) * 8;
        #pragma unroll
        for (int it = 0; it < 4; ++it) {
            int row = it * 16 + (tid >> 4);
            const float4* s = (const float4*)(vp + row * DD + col);
            float4 a = s[0], b = s[1];
            union { bf16x8 v8; ushort_t u[8]; } p;
            p.u[0] = f2bf(a.x); p.u[1] = f2bf(a.y); p.u[2] = f2bf(a.z); p.u[3] = f2bf(a.w);
            p.u[4] = f2bf(b.x); p.u[5] = f2bf(b.y); p.u[6] = f2bf(b.z); p.u[7] = f2bf(b.w);
            *(bf16x8*)&t[row * T_STR + col] = p.v8;
        }
    }
    __syncthreads();
    {
        int d = tid >> 1, seg = tid & 1;
        ushort_t* dst = vt + ((size_t)h * DD + d) * SEQL + sb * 64 + seg * 32;
        #pragma unroll
        for (int i = 0; i < 4; ++i) {
            union { bf16x8 v8; ushort_t u[8]; } o;
            #pragma unroll
            for (int e = 0; e < 8; ++e)
                o.u[e] = t[(seg * 32 + i * 8 + e) * T_STR + d];
            *(bf16x8*)(dst + i * 8) = o.v8;
        }
    }
}

// ---------------- main kernel: 48KB LDS (K dbuf + V single), split-K for qb>=14 ----------------
__global__ __launch_bounds__(256, 3)
void bsattn12(const float* __restrict__ q, const ushort_t* __restrict__ kbuf,
              const ushort_t* __restrict__ vtbuf, const float* __restrict__ scl,
              float* __restrict__ out, float* __restrict__ part, float* __restrict__ lws) {
    const int g = blockIdx.x;
    const int h = g & 7;
    const int u = g >> 3;
    // units: u<14 -> single qb = 13-u ; else split: qb = 63 - (u-14)/2, sidx = (u-14)&1
    int qb, sidx;
    if (u < SPLIT_Q0) { qb = SPLIT_Q0 - 1 - u; sidx = -1; }
    else { int v = u - SPLIT_Q0; qb = NBLK - 1 - (v >> 1); sidx = v & 1; }

    const int tid = threadIdx.x;
    const int w  = tid >> 6;
    const int l  = tid & 63;
    const int lr = l & 15;
    const int lg = l >> 4;

    __shared__ char smem[49152];
    // K dbuf: [0,32768)  two 16KB tiles (64 rows x 256B, swizzled)
    // V:      [32768,49152) one 16KB tile (128 rows x 128B, swizzled)
    // epilogue reuses smem as float [4][16][EP_STR] (33792B)

    const float kappa = scl[0] * 1.44269504088896f;

    const float*    qh = q     + (size_t)h * SEQL * DD;
    const ushort_t* kh = kbuf  + (size_t)h * SEQL * DD;
    const ushort_t* vh = vtbuf + (size_t)h * DD * SEQL;
    float*          oh = out   + (size_t)h * SEQL * DD;

    // active-list geometry
    const int vstart = (7 - h) & 7;
    const int lo = (qb >= 15) ? (qb - 15) : 0;
    const int nl = (qb + 1 < LOCAL_B) ? (qb + 1) : LOCAL_B;
    const int nv = (qb - LOCAL_B >= vstart) ? ((qb - LOCAL_B - vstart) >> 3) + 1 : 0;
    const int n  = nv + nl;
    int t0 = 0, t1 = n;
    if (sidx == 0) t1 = (n + 1) >> 1;
    else if (sidx == 1) t0 = (n + 1) >> 1;

    // Q -> B-fragments, prescaled by kappa (wave w owns q cols 16w..16w+15)
    bf16x8 qf[4];
    {
        const float* qrow = qh + (size_t)(qb * 64 + 16 * w + lr) * DD;
        #pragma unroll
        for (int ks = 0; ks < 4; ++ks) {
            const float4* p4 = (const float4*)(qrow + ks * 32 + lg * 8);
            float4 x = p4[0], y = p4[1];
            union { bf16x8 v8; ushort_t u[8]; } pk;
            pk.u[0] = f2bf(x.x * kappa); pk.u[1] = f2bf(x.y * kappa);
            pk.u[2] = f2bf(x.z * kappa); pk.u[3] = f2bf(x.w * kappa);
            pk.u[4] = f2bf(y.x * kappa); pk.u[5] = f2bf(y.y * kappa);
            pk.u[6] = f2bf(y.z * kappa); pk.u[7] = f2bf(y.w * kappa);
            qf[ks] = pk.v8;
        }
    }

    f32x4 oacc[8];   // O^T numerator (this unit's chunk): row d = 16dt+4lg+j, col q = lr
    #pragma unroll
    for (int i = 0; i < 8; ++i) oacc[i] = (f32x4){0.f, 0.f, 0.f, 0.f};
    float lrun = 0.f;

    const unsigned swz = (unsigned)((lg * 16) ^ ((lr & 7) << 4));
    unsigned kA = (unsigned)(lr * 256) + swz;      // flips ^16384 per iter
    unsigned kB = kA ^ 64u;
    const unsigned vA = 32768u + (unsigned)(lr * 128) + swz;   // single buffer
    const unsigned vB = vA ^ 64u;

    auto kb_of = [&](int i) { return (i < nv) ? (vstart + 8 * i) : (lo + (i - nv)); };

    auto stageK = [&](int kb_, unsigned dst) {
        const char* kbase = (const char*)(kh + (size_t)kb_ * 64 * DD);
        #pragma unroll
        for (int j = 0; j < 4; ++j) {
            int row = w * 16 + j * 4 + (l >> 4);
            int col = (l & 15) * 16;
            gload16(kbase + row * 256 + (col ^ ((row & 7) << 4)),
                    smem + dst + (w * 16 + j * 4) * 256);
        }
    };
    auto stageV = [&](int kb_) {
        const char* vbase = (const char*)vh + (size_t)kb_ * 128;
        #pragma unroll
        for (int j = 0; j < 4; ++j) {
            int d0 = w * 32 + j * 8;
            int d  = d0 + (l >> 3);
            int c  = (l & 7) * 16;
            gload16(vbase + (size_t)d * (SEQL * 2) + (c ^ ((d & 7) << 4)),
                    smem + 32768 + d0 * 128);
        }
    };

    const bool selA = (lg >= 2);
    const bool b1 = (lg & 1);
    const bool b2 = (lg & 2);

    // ---- prologue: K(first) into buf0 ----
    int kb = kb_of(t0);
    stageK(kb, 0);
    asm volatile("s_waitcnt vmcnt(0)" ::: "memory");
    __builtin_amdgcn_sched_barrier(0);
    __builtin_amdgcn_s_barrier();
    unsigned kst = 16384u;

    for (int t = t0; t < t1; ++t) {
        const bool haveNext = (t + 1 < t1);
        const int  knext = haveNext ? kb_of(t + 1) : -1;
        const bool diag = (kb == qb);

        // issue V(t) then K(t+1): V is the older group -> vmcnt(4) drains V
        stageV(kb);
        if (haveNext) stageK(knext, kst);

        // ---- QK^T + softmax + pack (K buffer already published) ----
        f32x4 sacc[4];
        #pragma unroll
        for (int ct = 0; ct < 4; ++ct)
            sacc[ct] = (f32x4){-MBIAS, -MBIAS, -MBIAS, -MBIAS};
        __builtin_amdgcn_s_setprio(1);
        #pragma unroll
        for (int ks = 0; ks < 4; ++ks) {
            #pragma unroll
            for (int ct = 0; ct < 4; ++ct) {
                bf16x8 kf = *(const bf16x8*)(smem + ((ks & 1) ? kB : kA) +
                                             ct * 4096 + (ks >> 1) * 128);
                sacc[ct] = __builtin_amdgcn_mfma_f32_16x16x32_bf16(kf, qf[ks], sacc[ct], 0, 0, 0);
            }
        }
        __builtin_amdgcn_s_setprio(0);

        float pv[4][4];
        #pragma unroll
        for (int ct = 0; ct < 4; ++ct)
            #pragma unroll
            for (int j = 0; j < 4; ++j)
                pv[ct][j] = exp2f(sacc[ct][j]);
        if (diag) {
            #pragma unroll
            for (int ct = 0; ct < 4; ++ct)
                #pragma unroll
                for (int j = 0; j < 4; ++j)
                    if (16 * ct + 4 * lg + j > 16 * w + lr) pv[ct][j] = 0.f;
        }
        float rs = 0.f;
        #pragma unroll
        for (int ct = 0; ct < 4; ++ct)
            #pragma unroll
            for (int j = 0; j < 4; ++j) rs += pv[ct][j];
        lrun += rs;

        unsigned e0 = cvtpk_bf16(pv[0][0], pv[0][1]), e1 = cvtpk_bf16(pv[0][2], pv[0][3]);
        unsigned e2 = cvtpk_bf16(pv[2][0], pv[2][1]), e3 = cvtpk_bf16(pv[2][2], pv[2][3]);
        unsigned o0 = cvtpk_bf16(pv[1][0], pv[1][1]), o1 = cvtpk_bf16(pv[1][2], pv[1][3]);
        unsigned o2 = cvtpk_bf16(pv[3][0], pv[3][1]), o3 = cvtpk_bf16(pv[3][2], pv[3][3]);

        union { unsigned u[4]; bf16x8 v8; } pb0, pb1;
        {
            unsigned m = selA ? o0 : e0, nn = selA ? e0 : o0;
            unsigned tt  = __shfl_xor((int)nn, 32);
            unsigned tp  = __shfl_xor((int)nn, 48);
            unsigned m16 = __shfl_xor((int)m, 16);
            pb0.u[0] = b1 ? (b2 ? m16 : tp) : (b2 ? tt : m);
            pb0.u[2] = b1 ? (b2 ? m : tt) : (b2 ? tp : m16);
        }
        {
            unsigned m = selA ? o1 : e1, nn = selA ? e1 : o1;
            unsigned tt  = __shfl_xor((int)nn, 32);
            unsigned tp  = __shfl_xor((int)nn, 48);
            unsigned m16 = __shfl_xor((int)m, 16);
            pb0.u[1] = b1 ? (b2 ? m16 : tp) : (b2 ? tt : m);
            pb0.u[3] = b1 ? (b2 ? m : tt) : (b2 ? tp : m16);
        }
        {
            unsigned m = selA ? o2 : e2, nn = selA ? e2 : o2;
            unsigned tt  = __shfl_xor((int)nn, 32);
            unsigned tp  = __shfl_xor((int)nn, 48);
            unsigned m16 = __shfl_xor((int)m, 16);
            pb1.u[0] = b1 ? (b2 ? m16 : tp) : (b2 ? tt : m);
            pb1.u[2] = b1 ? (b2 ? m : tt) : (b2 ? tp : m16);
        }
        {
            unsigned m = selA ? o3 : e3, nn = selA ? e3 : o3;
            unsigned tt  = __shfl_xor((int)nn, 32);
            unsigned tp  = __shfl_xor((int)nn, 48);
            unsigned m16 = __shfl_xor((int)m, 16);
            pb1.u[1] = b1 ? (b2 ? m16 : tp) : (b2 ? tt : m);
            pb1.u[3] = b1 ? (b2 ? m : tt) : (b2 ? tp : m16);
        }

        // ---- wait V(t) staged (own 4 oldest loads), publish, then PV ----
        if (haveNext) asm volatile("s_waitcnt vmcnt(4)" ::: "memory");
        else          asm volatile("s_waitcnt vmcnt(0)" ::: "memory");
        __builtin_amdgcn_sched_barrier(0);
        __builtin_amdgcn_s_barrier();
        __builtin_amdgcn_sched_barrier(0);

        __builtin_amdgcn_s_setprio(1);
        #pragma unroll
        for (int dt = 0; dt < 8; ++dt) {
            bf16x8 vf = *(const bf16x8*)(smem + vA + dt * 2048);
            oacc[dt] = __builtin_amdgcn_mfma_f32_16x16x32_bf16(vf, pb0.v8, oacc[dt], 0, 0, 0);
        }
        #pragma unroll
        for (int dt = 0; dt < 8; ++dt) {
            bf16x8 vf = *(const bf16x8*)(smem + vB + dt * 2048);
            oacc[dt] = __builtin_amdgcn_mfma_f32_16x16x32_bf16(vf, pb1.v8, oacc[dt], 0, 0, 0);
        }
        __builtin_amdgcn_s_setprio(0);

        // ---- drain K(t+1), publish; release V buffer for next iter ----
        asm volatile("s_waitcnt vmcnt(0)" ::: "memory");
        __builtin_amdgcn_sched_barrier(0);
        __builtin_amdgcn_s_barrier();

        kA ^= 16384u; kB ^= 16384u; kst ^= 16384u;
        kb = knext;
    }

    // per-lane partial row-sum -> row sum for q = 16w+lr over this chunk
    float tot = lrun;
    tot += __shfl_xor(tot, 16);
    tot += __shfl_xor(tot, 32);
    {
        float* ls = lws + ((size_t)(h * NBLK + qb) * 2 + (sidx == 1 ? 1 : 0)) * 64;
        if (lg == 0) ls[w * 16 + lr] = tot;
    }

    // epilogue: raw numerator, transpose via LDS for coalesced stores
    __syncthreads();
    float* ep  = (float*)smem;
    float* epw = ep + w * 16 * EP_STR;
    #pragma unroll
    for (int dt = 0; dt < 8; ++dt)
        #pragma unroll
        for (int j = 0; j < 4; ++j)
            epw[lr * EP_STR + dt * 16 + 4 * lg + j] = oacc[dt][j];
    __syncthreads();
    {
        float* obase = (sidx == 1)
            ? part + (size_t)(h * NSPLIT + (qb - SPLIT_Q0)) * 8192
            : oh + (size_t)qb * 64 * DD;
        int qr  = tid >> 2;
        int seg = tid & 3;
        const float* rp = ep + (qr >> 4) * (16 * EP_STR) + (qr & 15) * EP_STR + seg * 32;
        float* op = obase + (size_t)qr * DD + seg * 32;
        #pragma unroll
        for (int i = 0; i < 8; ++i)
            ((float4*)op)[i] = ((const float4*)rp)[i];
    }
}

// ---------------- merge + normalize ----------------
__global__ void merge(float* __restrict__ out, const float* __restrict__ part,
                      const float* __restrict__ lws) {
    int b  = blockIdx.x;
    int h  = b & 7;
    int qb = b >> 3;
    int tid = threadIdx.x;
    int r = tid >> 2, seg = tid & 3;
    const float* lrow = lws + (size_t)(h * NBLK + qb) * 128;
    bool sp = (qb >= SPLIT_Q0);
    float denom = lrow[r] + (sp ? lrow[64 + r] : 0.f);
    float rcp = 1.0f / denom;
    float* op = out + ((size_t)h * SEQL + qb * 64 + r) * DD + seg * 32;
    const float* pp = part + (size_t)(h * NSPLIT + (qb - SPLIT_Q0)) * 8192 + (size_t)r * DD + seg * 32;
    #pragma unroll
    for (int i = 0; i < 8; ++i) {
        float4 a = ((const float4*)op)[i];
        if (sp) {
            float4 c = ((const float4*)pp)[i];
            a.x += c.x; a.y += c.y; a.z += c.z; a.w += c.w;
        }
        a.x *= rcp; a.y *= rcp; a.z *= rcp; a.w *= rcp;
        ((float4*)op)[i] = a;
    }
}

extern "C" void kernel_launch(void* const* d_in, const int* in_sizes, int n_in,
                              void* d_out, int out_size, void* d_ws, size_t ws_size,
                              hipStream_t stream) {
    const float* q   = (const float*)d_in[0];
    const float* k   = (const float*)d_in[1];
    const float* v   = (const float*)d_in[2];
    const float* scl = (const float*)d_in[3];
    float* out = (float*)d_out;

    ushort_t* Kb = (ushort_t*)d_ws;                          // 8.4 MB bf16 K
    ushort_t* Vt = Kb + (size_t)HH * SEQL * DD;              // 8.4 MB bf16 V^T
    float* part  = (float*)(Vt + (size_t)HH * SEQL * DD);    // 13.1 MB split-1 partials
    float* lws   = part + (size_t)HH * NSPLIT * 8192;        // 256 KB row sums

    prep<<<dim3(2048 + HH * 64), dim3(256), 0, stream>>>(k, v, Kb, Vt);
    bsattn12<<<dim3(HH * UNITS_PER_H), dim3(256), 0, stream>>>(q, Kb, Vt, scl, out, part, lws);
    merge<<<dim3(HH * NBLK), dim3(256), 0, stream>>>(out, part, lws);
}